// Round 2
// baseline (192.831 us; speedup 1.0000x reference)
//
#include <hip/hip_runtime.h>
#include <math.h>

#define NROWS 32768
#define HID   1024
#define P4    4096

__device__ __forceinline__ float fast_tanh(float x) {
    // tanh(x) = sign(x) * (1 - e) / (1 + e),  e = exp(-2|x|) in (0,1] -> no overflow
    float e = __expf(-2.0f * fabsf(x));
    float t = (1.0f - e) * __builtin_amdgcn_rcpf(1.0f + e);
    return copysignf(t, x);
}

// ---------------------------------------------------------------------------
// Kernel 1: per-factor S_i[8][8] then rhs[4096]. One block, 256 threads.
// ---------------------------------------------------------------------------
__global__ __launch_bounds__(256) void k_factors_rhs(
    const float* __restrict__ eq,
    const float* __restrict__ qx0, const float* __restrict__ wa0, const float* __restrict__ ba0,
    const float* __restrict__ wb0, const float* __restrict__ bb0,
    const float* __restrict__ qx1, const float* __restrict__ wa1, const float* __restrict__ ba1,
    const float* __restrict__ wb1, const float* __restrict__ bb1,
    const float* __restrict__ qx2, const float* __restrict__ wa2, const float* __restrict__ ba2,
    const float* __restrict__ wb2, const float* __restrict__ bb2,
    const float* __restrict__ qx3, const float* __restrict__ wa3, const float* __restrict__ ba3,
    const float* __restrict__ wb3, const float* __restrict__ bb3,
    float* __restrict__ rhs)
{
    __shared__ float S[4][64];
    __shared__ float y[64];
    __shared__ float wh[128];
    __shared__ float ysum;

    const float* QX[4] = {qx0, qx1, qx2, qx3};
    const float* WA[4] = {wa0, wa1, wa2, wa3};
    const float* BA[4] = {ba0, ba1, ba2, ba3};
    const float* WB[4] = {wb0, wb1, wb2, wb3};
    const float* BB[4] = {bb0, bb1, bb2, bb3};

    const int t = threadIdx.x;
    const float eqv = eq[0];

    for (int f = 0; f < 4; ++f) {
        const float* qx = QX[f];
        if (t < 64) y[t] = eqv * sinf((float)M_PI * qx[t]);
        __syncthreads();
        if (t < 128) {
            float w = WA[f][t], b = BA[f][t], acc = 0.f;
            for (int p = 0; p < 64; ++p)
                acc += y[p] * tanhf(fmaf(qx[p], w, b));
            wh[t] = acc;
        } else if (t == 128) {
            float s = 0.f;
            for (int p = 0; p < 64; ++p) s += y[p];
            ysum = s;
        }
        __syncthreads();
        if (t < 64) {
            float acc = BB[f][t] * ysum;
            for (int h = 0; h < 128; ++h)
                acc = fmaf(wh[h], WB[f][h * 64 + t], acc);
            S[f][t] = acc;
        }
        __syncthreads();
    }

    // rhs[((b*8+d)*8+fq)*8+m] = sum_x S0[b,x] S1[d,x] S2[fq,x] S3[m,x]
    for (int i = t; i < P4; i += 256) {
        int m  = i & 7;
        int fq = (i >> 3) & 7;
        int d  = (i >> 6) & 7;
        int b  = (i >> 9) & 7;
        float acc = 0.f;
        #pragma unroll
        for (int x = 0; x < 8; ++x)
            acc += S[0][b * 8 + x] * S[1][d * 8 + x] * S[2][fq * 8 + x] * S[3][m * 8 + x];
        rhs[i] = acc;
    }
}

// ---------------------------------------------------------------------------
// Kernel 2: w2r[1024] = W2 @ rhs (one wave per row), b2r = b2 . rhs
// grid = 257 blocks x 256 threads; block 256 does b2r.
// ---------------------------------------------------------------------------
__global__ __launch_bounds__(256) void k_w2r(
    const float* __restrict__ W2, const float* __restrict__ b2,
    const float* __restrict__ rhs, float* __restrict__ w2r, float* __restrict__ b2r)
{
    const int wave = threadIdx.x >> 6;
    const int lane = threadIdx.x & 63;

    if (blockIdx.x == 256) {
        if (wave != 0) return;
        float acc = 0.f;
        for (int k = lane; k < P4; k += 64) acc += b2[k] * rhs[k];
        #pragma unroll
        for (int off = 32; off; off >>= 1) acc += __shfl_down(acc, off);
        if (lane == 0) *b2r = acc;
        return;
    }

    const int row = blockIdx.x * 4 + wave;
    const float4* w4 = (const float4*)(W2 + (size_t)row * P4);
    const float4* r4 = (const float4*)rhs;
    float acc = 0.f;
    #pragma unroll 4
    for (int k = lane; k < P4 / 4; k += 64) {
        float4 a = w4[k];
        float4 b = r4[k];
        acc += a.x * b.x + a.y * b.y + a.z * b.z + a.w * b.w;
    }
    #pragma unroll
    for (int off = 32; off; off >>= 1) acc += __shfl_down(acc, off);
    if (lane == 0) w2r[row] = acc;
}

// ---------------------------------------------------------------------------
// Kernel 3: out[n] = b2r + sum_h tanh(x . W1[:,h] + b1[h]) * w2r[h]
// 512 blocks x 256 threads. Block handles 64 rows; wave w handles h-chunk w
// (256 h's). Uniform h per wave -> W1/b1/w2r become scalar (s_load) reads.
// ---------------------------------------------------------------------------
__global__ __launch_bounds__(256) void k_out(
    const float* __restrict__ input,
    const float* __restrict__ W1, const float* __restrict__ b1,
    const float* __restrict__ w2r, const float* __restrict__ b2r,
    float* __restrict__ out)
{
    const int t = threadIdx.x;
    const int lane = t & 63;
    const int wave = __builtin_amdgcn_readfirstlane(t >> 6);  // force SGPR

    const int row = blockIdx.x * 64 + lane;
    const float* x = input + (size_t)row * 3;
    const float x0 = x[0], x1 = x[1], x2 = x[2];

    const int h0 = wave * 256;
    float acc = 0.f;
    #pragma unroll 4
    for (int h = h0; h < h0 + 256; ++h) {
        float w0 = W1[h];
        float w1 = W1[HID + h];
        float w2 = W1[2 * HID + h];
        float bb = b1[h];
        float pre = fmaf(x0, w0, fmaf(x1, w1, fmaf(x2, w2, bb)));
        acc = fmaf(fast_tanh(pre), w2r[h], acc);
    }

    __shared__ float part[4][64];
    part[wave][lane] = acc;
    __syncthreads();
    if (t < 64) {
        float r = part[0][t] + part[1][t] + part[2][t] + part[3][t] + b2r[0];
        out[blockIdx.x * 64 + t] = r;
    }
}

// ---------------------------------------------------------------------------
extern "C" void kernel_launch(void* const* d_in, const int* in_sizes, int n_in,
                              void* d_out, int out_size, void* d_ws, size_t ws_size,
                              hipStream_t stream)
{
    const float* input = (const float*)d_in[0];
    const float* eq    = (const float*)d_in[1];
    const float* W1    = (const float*)d_in[2];
    const float* b1    = (const float*)d_in[3];
    const float* W2    = (const float*)d_in[4];
    const float* b2    = (const float*)d_in[5];
    const float* q[4][5];
    for (int i = 0; i < 4; ++i)
        for (int k = 0; k < 5; ++k)
            q[i][k] = (const float*)d_in[6 + 5 * i + k];

    float* ws  = (float*)d_ws;
    float* rhs = ws;            // 4096
    float* w2r = ws + 4096;     // 1024
    float* b2r = ws + 5120;     // 1
    float* out = (float*)d_out;

    hipLaunchKernelGGL(k_factors_rhs, dim3(1), dim3(256), 0, stream,
        eq,
        q[0][0], q[0][1], q[0][2], q[0][3], q[0][4],
        q[1][0], q[1][1], q[1][2], q[1][3], q[1][4],
        q[2][0], q[2][1], q[2][2], q[2][3], q[2][4],
        q[3][0], q[3][1], q[3][2], q[3][3], q[3][4],
        rhs);

    hipLaunchKernelGGL(k_w2r, dim3(257), dim3(256), 0, stream,
        W2, b2, rhs, w2r, b2r);

    hipLaunchKernelGGL(k_out, dim3(512), dim3(256), 0, stream,
        input, W1, b1, w2r, b2r, out);
}

// Round 3
// 143.786 us; speedup vs baseline: 1.3411x; 1.3411x over previous
//
#include <hip/hip_runtime.h>
#include <math.h>

#define HID   1024
#define P4    4096

__device__ __forceinline__ float fast_tanh(float x) {
    // tanh(x) = sign(x) * (1 - e) / (1 + e),  e = exp(-2|x|) in (0,1] -> no overflow
    float e = __expf(-2.0f * fabsf(x));
    float t = (1.0f - e) * __builtin_amdgcn_rcpf(1.0f + e);
    return copysignf(t, x);
}

// ---------------------------------------------------------------------------
// Kernel 1: per-factor S_i[8][8] (wave f handles factor f), then rhs[4096]
// and b2r = b2 . rhs. One block, 256 threads = 4 waves.
// ---------------------------------------------------------------------------
__global__ __launch_bounds__(256) void k_factors_rhs(
    const float* __restrict__ eq,
    const float* __restrict__ qx0, const float* __restrict__ wa0, const float* __restrict__ ba0,
    const float* __restrict__ wb0, const float* __restrict__ bb0,
    const float* __restrict__ qx1, const float* __restrict__ wa1, const float* __restrict__ ba1,
    const float* __restrict__ wb1, const float* __restrict__ bb1,
    const float* __restrict__ qx2, const float* __restrict__ wa2, const float* __restrict__ ba2,
    const float* __restrict__ wb2, const float* __restrict__ bb2,
    const float* __restrict__ qx3, const float* __restrict__ wa3, const float* __restrict__ ba3,
    const float* __restrict__ wb3, const float* __restrict__ bb3,
    const float* __restrict__ b2,
    float* __restrict__ rhs, float* __restrict__ b2r)
{
    __shared__ float2 qy_s[4][64];   // {qx, y}
    __shared__ float  wh_s[4][128];
    __shared__ float  S_s[4][64];
    __shared__ float  red[256];

    const int t    = threadIdx.x;
    const int lane = t & 63;
    const int f    = t >> 6;          // wave index = factor index (wave-uniform)

    const float* qx; const float* wa; const float* ba; const float* wb; const float* bb;
    if (f == 0)      { qx = qx0; wa = wa0; ba = ba0; wb = wb0; bb = bb0; }
    else if (f == 1) { qx = qx1; wa = wa1; ba = ba1; wb = wb1; bb = bb1; }
    else if (f == 2) { qx = qx2; wa = wa2; ba = ba2; wb = wb2; bb = bb2; }
    else             { qx = qx3; wa = wa3; ba = ba3; wb = wb3; bb = bb3; }

    // stage 1: y[p] = eq * sin(pi * qx[p]); one lane per quad point
    const float qv = qx[lane];
    const float yv = eq[0] * sinf((float)M_PI * qv);
    qy_s[f][lane] = make_float2(qv, yv);

    // ysum across the wave (all lanes end with the total)
    float ysum = yv;
    #pragma unroll
    for (int off = 32; off; off >>= 1) ysum += __shfl_xor(ysum, off);

    __syncthreads();

    // stage 2: hidden units; lane handles h = lane and h = lane+64
    {
        const float w0 = wa[lane],      c0 = ba[lane];
        const float w1 = wa[lane + 64], c1 = ba[lane + 64];
        float a0 = 0.f, a1 = 0.f;
        #pragma unroll 8
        for (int p = 0; p < 64; ++p) {
            float2 qy = qy_s[f][p];                 // LDS broadcast
            a0 += qy.y * fast_tanh(fmaf(qy.x, w0, c0));
            a1 += qy.y * fast_tanh(fmaf(qy.x, w1, c1));
        }
        wh_s[f][lane]      = a0;
        wh_s[f][lane + 64] = a1;
    }
    __syncthreads();

    // stage 3: output layer; lane j of wave f computes S_f[j]
    {
        float acc = bb[lane] * ysum;
        #pragma unroll 8
        for (int h = 0; h < 128; ++h)
            acc = fmaf(wh_s[f][h], wb[h * 64 + lane], acc);  // wb coalesced
        S_s[f][lane] = acc;
    }
    __syncthreads();

    // stage 4: rhs[((b*8+d)*8+fq)*8+m] = sum_x S0[b,x] S1[d,x] S2[fq,x] S3[m,x]
    // plus local partial of b2 . rhs
    float local = 0.f;
    for (int i = t; i < P4; i += 256) {
        const int m  = i & 7;
        const int fq = (i >> 3) & 7;
        const int d  = (i >> 6) & 7;
        const int b  = (i >> 9) & 7;
        float acc = 0.f;
        #pragma unroll
        for (int x = 0; x < 8; ++x)
            acc += S_s[0][b * 8 + x] * S_s[1][d * 8 + x]
                 * S_s[2][fq * 8 + x] * S_s[3][m * 8 + x];
        rhs[i] = acc;
        local = fmaf(b2[i], acc, local);
    }

    // block-reduce local -> b2r
    red[t] = local;
    __syncthreads();
    if (t < 128) red[t] += red[t + 128];
    __syncthreads();
    if (t < 64) {
        float v = red[t] + red[t + 64];
        #pragma unroll
        for (int off = 32; off; off >>= 1) v += __shfl_xor(v, off);
        if (t == 0) b2r[0] = v;
    }
}

// ---------------------------------------------------------------------------
// Kernel 2: w2r[1024] = W2 @ rhs. 256 blocks x 4 waves; one wave per row.
// ---------------------------------------------------------------------------
__global__ __launch_bounds__(256) void k_w2r(
    const float* __restrict__ W2, const float* __restrict__ rhs,
    float* __restrict__ w2r)
{
    const int wave = threadIdx.x >> 6;
    const int lane = threadIdx.x & 63;
    const int row  = blockIdx.x * 4 + wave;

    const float4* w4 = (const float4*)(W2 + (size_t)row * P4);
    const float4* r4 = (const float4*)rhs;

    float acc = 0.f;
    #pragma unroll
    for (int i = 0; i < 16; ++i) {           // all 16 loads issue back-to-back
        const int k = lane + 64 * i;
        float4 a = w4[k];
        float4 b = r4[k];
        acc += a.x * b.x + a.y * b.y + a.z * b.z + a.w * b.w;
    }
    #pragma unroll
    for (int off = 32; off; off >>= 1) acc += __shfl_down(acc, off);
    if (lane == 0) w2r[row] = acc;
}

// ---------------------------------------------------------------------------
// Kernel 3: out[n] = b2r + sum_h tanh(x . W1[:,h] + b1[h]) * w2r[h]
// 512 blocks x 256 threads; 64 rows/block, wave w owns h in [256w, 256w+256).
// W1^T/b1 packed as float4 + w2r staged in LDS (broadcast reads, 0 conflicts).
// ---------------------------------------------------------------------------
__global__ __launch_bounds__(256) void k_out(
    const float* __restrict__ input,
    const float* __restrict__ W1, const float* __restrict__ b1,
    const float* __restrict__ w2r, const float* __restrict__ b2r,
    float* __restrict__ out)
{
    __shared__ float4 wpack[HID];   // {W1[0,h], W1[1,h], W1[2,h], b1[h]}
    __shared__ float  w2rs[HID];
    __shared__ float  part[4][64];

    const int t = threadIdx.x;
    #pragma unroll
    for (int h = t; h < HID; h += 256) {
        wpack[h] = make_float4(W1[h], W1[HID + h], W1[2 * HID + h], b1[h]);
        w2rs[h]  = w2r[h];
    }
    __syncthreads();

    const int lane = t & 63;
    const int wave = t >> 6;
    const int row  = blockIdx.x * 64 + lane;
    const float* x = input + (size_t)row * 3;
    const float x0 = x[0], x1 = x[1], x2 = x[2];

    float acc = 0.f;
    const int h0 = wave * 256;
    #pragma unroll 8
    for (int h = h0; h < h0 + 256; ++h) {
        float4 wp = wpack[h];                         // ds_read_b128 broadcast
        float pre = fmaf(x0, wp.x, fmaf(x1, wp.y, fmaf(x2, wp.z, wp.w)));
        acc = fmaf(fast_tanh(pre), w2rs[h], acc);
    }

    part[wave][lane] = acc;
    __syncthreads();
    if (t < 64)
        out[blockIdx.x * 64 + t] =
            part[0][t] + part[1][t] + part[2][t] + part[3][t] + b2r[0];
}

// ---------------------------------------------------------------------------
extern "C" void kernel_launch(void* const* d_in, const int* in_sizes, int n_in,
                              void* d_out, int out_size, void* d_ws, size_t ws_size,
                              hipStream_t stream)
{
    const float* input = (const float*)d_in[0];
    const float* eq    = (const float*)d_in[1];
    const float* W1    = (const float*)d_in[2];
    const float* b1    = (const float*)d_in[3];
    const float* W2    = (const float*)d_in[4];
    const float* b2    = (const float*)d_in[5];
    const float* q[4][5];
    for (int i = 0; i < 4; ++i)
        for (int k = 0; k < 5; ++k)
            q[i][k] = (const float*)d_in[6 + 5 * i + k];

    float* ws  = (float*)d_ws;
    float* rhs = ws;            // 4096
    float* w2r = ws + 4096;     // 1024
    float* b2r = ws + 5120;     // 1
    float* out = (float*)d_out;

    hipLaunchKernelGGL(k_factors_rhs, dim3(1), dim3(256), 0, stream,
        eq,
        q[0][0], q[0][1], q[0][2], q[0][3], q[0][4],
        q[1][0], q[1][1], q[1][2], q[1][3], q[1][4],
        q[2][0], q[2][1], q[2][2], q[2][3], q[2][4],
        q[3][0], q[3][1], q[3][2], q[3][3], q[3][4],
        b2, rhs, b2r);

    hipLaunchKernelGGL(k_w2r, dim3(256), dim3(256), 0, stream,
        W2, rhs, w2r);

    hipLaunchKernelGGL(k_out, dim3(512), dim3(256), 0, stream,
        input, W1, b1, w2r, b2r, out);
}